// Round 19
// baseline (69.814 us; speedup 1.0000x reference)
//
#include <hip/hip_runtime.h>
#include <hip/hip_cooperative_groups.h>

namespace cg = cooperative_groups;

#define B_    4
#define N_    1024
#define FIN   128
#define FOUT  256
#define NH    8
#define ND    32
#define NSL   0.2f
#define LOG2E 1.44269504088896340736f

typedef _Float16 half8 __attribute__((ext_vector_type(8)));
typedef _Float16 h2 __attribute__((ext_vector_type(2)));
typedef __fp16 fp16x2 __attribute__((ext_vector_type(2)));
typedef float f32x4 __attribute__((ext_vector_type(4)));

static __device__ __forceinline__ unsigned bc_u(h2 v) {
  union { h2 h; unsigned u; } c; c.h = v; return c.u;
}
static __device__ __forceinline__ h2 bc_h(unsigned v) {
  union { h2 h; unsigned u; } c; c.u = v; return c.h;
}

#define MASKW(SH, Q)                                                            \
  __builtin_amdgcn_perm(                                                        \
      (unsigned)__builtin_amdgcn_sbfe((int)(SH), 2*(Q)+1, 1),                   \
      (unsigned)__builtin_amdgcn_sbfe((int)(SH), 2*(Q), 1), 0x07060100u)

#define PGEN_PAIR(EL2, ERW, MAW, OUTW)                                          \
  {                                                                             \
    h2 x = (EL2) + bc_h(ERW);                                                   \
    h2 y = x * nsl2;                                                            \
    x = __builtin_elementwise_max(x, y);                                        \
    const unsigned xu = bc_u(x);                                                \
    const unsigned xh = xu >> 16;                                               \
    unsigned plo, phi;                                                          \
    asm("v_exp_f16 %0, %1" : "=v"(plo) : "v"(xu));                              \
    asm("v_exp_f16 %0, %1" : "=v"(phi) : "v"(xh));                              \
    (OUTW) = __builtin_amdgcn_perm(phi, plo, 0x05040100u) & (MAW);              \
  }

// ---------- phase-2 body as a macro-free inline (shared by fused & fallback) ----------
struct P2Smem {
  _Float16 er_h[N_];
  float dpart[8][32][68];
  float denp[8][64];
};

static __device__ __forceinline__ void kc_body(
    P2Smem* s2, const unsigned* __restrict__ adjb, const _Float16* __restrict__ g16,
    const float* __restrict__ elt, const float* __restrict__ ert,
    float* __restrict__ out, int b, int head, int i0,
    int t, int w16, int lane, int li, int kg, int kg8)
{
  const int hb = b * NH + head;
  const int wv = w16 >> 1;
  const int ih = w16 & 1;
  const h2 nsl2 = {(_Float16)NSL, (_Float16)NSL};

  s2->er_h[t] = (_Float16)ert[(size_t)hb * N_ + t];
  __syncthreads();

  const int rowA = i0 + ih * 32 + li;
  const int rowB = rowA + 16;
  const float el_a = elt[(size_t)hb * N_ + rowA];
  const float el_b = elt[(size_t)hb * N_ + rowB];
  union { fp16x2 hh; unsigned u; h2 h; } ca, cb;
  ca.hh = __builtin_amdgcn_cvt_pkrtz(el_a, el_a);
  cb.hh = __builtin_amdgcn_cvt_pkrtz(el_b, el_b);
  const h2 el2a = ca.h, el2b = cb.h;

  const int4 A  = ((const int4*)(adjb + (size_t)(b * N_ + rowA) * 32))[wv];
  const int4 Bm = ((const int4*)(adjb + (size_t)(b * N_ + rowB) * 32))[wv];
  const unsigned wA[4] = {(unsigned)A.x, (unsigned)A.y, (unsigned)A.z, (unsigned)A.w};
  const unsigned wB[4] = {(unsigned)Bm.x, (unsigned)Bm.y, (unsigned)Bm.z, (unsigned)Bm.w};

  const _Float16* __restrict__ arow0 =
      g16 + ((size_t)hb * ND + li) * N_ + wv * 128 + kg8;
  const _Float16* __restrict__ arow1 = arow0 + (size_t)16 * N_;

  f32x4 acc0 = {0,0,0,0}, acc1 = {0,0,0,0}, accd = {0,0,0,0};
  f32x4 acc0b = {0,0,0,0}, acc1b = {0,0,0,0}, accdb = {0,0,0,0};
  const half8 ones = {(_Float16)1.f, (_Float16)1.f, (_Float16)1.f, (_Float16)1.f,
                      (_Float16)1.f, (_Float16)1.f, (_Float16)1.f, (_Float16)1.f};

#pragma unroll
  for (int u = 0; u < 4; ++u) {
    const half8 Ag0 = *(const half8*)(arow0 + u * 32);
    const half8 Ag1 = *(const half8*)(arow1 + u * 32);
    const uint4 erv = *(const uint4*)&s2->er_h[wv * 128 + u * 32 + kg8];
    const unsigned erw[4] = {erv.x, erv.y, erv.z, erv.w};
    const unsigned shA = wA[u] >> kg8;
    const unsigned shB = wB[u] >> kg8;

    union { half8 h8; unsigned uu[4]; } PA, PB;
#pragma unroll
    for (int q = 0; q < 4; ++q) {
      const unsigned maA = MASKW(shA, q);
      const unsigned maB = MASKW(shB, q);
      PGEN_PAIR(el2a, erw[q], maA, PA.uu[q])
      PGEN_PAIR(el2b, erw[q], maB, PB.uu[q])
    }

    acc0  = __builtin_amdgcn_mfma_f32_16x16x32_f16(Ag0, PA.h8, acc0, 0, 0, 0);
    acc1  = __builtin_amdgcn_mfma_f32_16x16x32_f16(Ag1, PA.h8, acc1, 0, 0, 0);
    accd  = __builtin_amdgcn_mfma_f32_16x16x32_f16(ones, PA.h8, accd, 0, 0, 0);
    acc0b = __builtin_amdgcn_mfma_f32_16x16x32_f16(Ag0, PB.h8, acc0b, 0, 0, 0);
    acc1b = __builtin_amdgcn_mfma_f32_16x16x32_f16(Ag1, PB.h8, acc1b, 0, 0, 0);
    accdb = __builtin_amdgcn_mfma_f32_16x16x32_f16(ones, PB.h8, accdb, 0, 0, 0);
  }

  const int ci = ih * 32 + li;
#pragma unroll
  for (int r = 0; r < 4; ++r) {
    s2->dpart[wv][4*kg + r][ci]           = acc0[r];
    s2->dpart[wv][16 + 4*kg + r][ci]      = acc1[r];
    s2->dpart[wv][4*kg + r][16 + ci]      = acc0b[r];
    s2->dpart[wv][16 + 4*kg + r][16 + ci] = acc1b[r];
  }
  if (lane < 16) { s2->denp[wv][ci] = accd[0]; s2->denp[wv][16 + ci] = accdb[0]; }
  __syncthreads();

  for (int o = t; o < 2048; o += 1024) {
    const int f = o & 31, ii = o >> 5;
    float s = 0.f, dn = 0.f;
#pragma unroll
    for (int p = 0; p < 8; ++p) { s += s2->dpart[p][f][ii]; dn += s2->denp[p][ii]; }
    float w = s / dn;
    w = fmaxf(w, NSL * w);
    out[((size_t)(b * N_ + i0 + ii)) * FOUT + head * ND + f] = w;
  }
  __syncthreads();   // LDS reuse by next unit
}

union SMemF {
  struct {                       // phase 1 (36.9 KB)
    _Float16 h16s[64][136];
    _Float16 wt16s[64][136];
    float elp[2][2][4][16];
    float erp[2][2][4][16];
  } p1;
  P2Smem p2;                     // phase 2 (73.7 KB)
};

// ---- fused cooperative kernel: 256 blocks x 1024 threads, 2 units/block ----
__global__ __launch_bounds__(1024) void gat_fused(
    const int* __restrict__ adj, unsigned long long* __restrict__ adjb64,
    const float* __restrict__ W, const float* __restrict__ h,
    const float* __restrict__ a_vec, _Float16* __restrict__ g16,
    float* __restrict__ elt, float* __restrict__ ert,
    float* __restrict__ out)
{
  __shared__ SMemF sm;

  const int t = threadIdx.x;
  const int u0 = blockIdx.x;            // 0..255
  const int xcd = u0 & 7;
  const int fq  = xcd & 3;
  const int b1  = xcd >> 2;
  const int sl0 = u0 >> 3;              // 0..31
  const int it  = sl0 & 15;
  const int hp  = (sl0 >> 4) & 1;
  const int head = fq * 2 + hp;
  const int i0   = it * 64;
  const int bnt0 = (it + 16 * hp) * 2;

  const int w16  = t >> 6;
  const int lane = t & 63;
  const int li = lane & 15, kg = lane >> 4, kg8 = kg * 8;

  // ================= PHASE 1 =================
  {   // stage h: 64 rows (2 units x 32), one half8 per thread
    const int r = t >> 4, hk = (t & 15) * 8;
    const int un_s = r >> 5, hr = r & 31;
    const size_t hrow = (size_t)((un_s * 2 + b1) * N_ + bnt0 * 16 + hr) * FIN;
    const float4 v0 = *(const float4*)&h[hrow + hk];
    const float4 v1 = *(const float4*)&h[hrow + hk + 4];
    half8 o;
    o[0]=(_Float16)v0.x; o[1]=(_Float16)v0.y; o[2]=(_Float16)v0.z; o[3]=(_Float16)v0.w;
    o[4]=(_Float16)v1.x; o[5]=(_Float16)v1.y; o[6]=(_Float16)v1.z; o[7]=(_Float16)v1.w;
    *(half8*)&sm.p1.h16s[r][hk] = o;
  }
  {   // stage W^T slice [fq*64..+64)[128]: 8 f32 per thread, lane-contiguous
    const int fl = t & 63;
    const int kk0 = (t >> 6) * 8;
#pragma unroll 8
    for (int kk = kk0; kk < kk0 + 8; ++kk)
      sm.p1.wt16s[fl][kk] = (_Float16)W[(size_t)kk * FOUT + fq * 64 + fl];
  }
  __syncthreads();

  if (w16 < 8) {     // gemm waves: 2 units each
    const int tsel = w16 >> 2;
    const int wv4  = w16 & 3;
    const int head_g = fq * 2 + (wv4 >> 1);
    const int fi0  = (wv4 & 1) * 16;
    const int nn   = (bnt0 + tsel) * 16;
    const _Float16* arow = &sm.p1.wt16s[wv4 * 16 + li][kg8];

#pragma unroll
    for (int un = 0; un < 2; ++un) {
      const int b  = un * 2 + b1;
      const int hb = b * NH + head_g;

      f32x4 acc = {0.f, 0.f, 0.f, 0.f};
#pragma unroll
      for (int ks = 0; ks < 4; ++ks) {
        const half8 Af = *(const half8*)(arow + ks * 32);
        const half8 Bf = *(const half8*)&sm.p1.h16s[un * 32 + tsel * 16 + li][ks * 32 + kg8];
        acc = __builtin_amdgcn_mfma_f32_16x16x32_f16(Af, Bf, acc, 0, 0, 0);
      }

      float pl = 0.f, pr = 0.f;
#pragma unroll
      for (int r = 0; r < 4; ++r) {
        const int fi = fi0 + kg * 4 + r;
        g16[((size_t)hb * ND + fi) * N_ + nn + li] = (_Float16)acc[r];
        pl += a_vec[fi] * acc[r];
        pr += a_vec[ND + fi] * acc[r];
      }
      pl *= LOG2E; pr *= LOG2E;
      pl += __shfl_xor(pl, 16); pl += __shfl_xor(pl, 32);
      pr += __shfl_xor(pr, 16); pr += __shfl_xor(pr, 32);
      if (lane < 16) { sm.p1.elp[un][tsel][wv4][li] = pl; sm.p1.erp[un][tsel][wv4][li] = pr; }
    }
  } else {           // pack waves: 2 iterations each
#pragma unroll
    for (int iter = 0; iter < 2; ++iter) {
      const int gwp = iter * 2048 + u0 * 8 + (w16 - 8);   // 0..4095
      const size_t base0 = (size_t)gwp * 1024;
#pragma unroll
      for (int itp = 0; itp < 16; ++itp) {
        const size_t base = base0 + itp * 64;
        const unsigned long long m = __ballot(adj[base + lane] != 0);
        if (lane == 0) adjb64[base >> 6] = m;
      }
    }
  }
  __syncthreads();

  if (t < 128) {     // combine el/er partials
    const int un = t >> 6, tsel = (t >> 5) & 1, hh = (t >> 4) & 1, ll = t & 15;
    const int hbw = (un * 2 + b1) * NH + fq * 2 + hh;
    const int nn = (bnt0 + tsel) * 16;
    elt[(size_t)hbw * N_ + nn + ll] =
        sm.p1.elp[un][tsel][2*hh][ll] + sm.p1.elp[un][tsel][2*hh+1][ll];
    ert[(size_t)hbw * N_ + nn + ll] =
        sm.p1.erp[un][tsel][2*hh][ll] + sm.p1.erp[un][tsel][2*hh+1][ll];
  }

  cg::this_grid().sync();

  // ================= PHASE 2: 2 kC units =================
#pragma unroll 1
  for (int un = 0; un < 2; ++un) {
    kc_body(&sm.p2, (const unsigned*)adjb64, g16, elt, ert, out,
            un * 2 + b1, head, i0, t, w16, lane, li, kg, kg8);
  }
}

// ================= FALLBACK (r17 two-kernel path, known-good) =================
__global__ __launch_bounds__(256) void gat_kAB(
    const int* __restrict__ adj, unsigned long long* __restrict__ adjb64,
    const float* __restrict__ W, const float* __restrict__ h,
    const float* __restrict__ a_vec, _Float16* __restrict__ g16,
    float* __restrict__ elt, float* __restrict__ ert)
{
  __shared__ _Float16 h16s[16][136];
  __shared__ _Float16 wt16s[64][136];
  __shared__ float elp[4][16], erp[4][16];

  const int t = threadIdx.x;
  if (blockIdx.x < 1024) {
    const int gw = (blockIdx.x * 256 + t) >> 6;
    const int lane = t & 63;
    const size_t base0 = (size_t)gw * 1024;
#pragma unroll
    for (int it = 0; it < 16; ++it) {
      const size_t base = base0 + it * 64;
      const unsigned long long m = __ballot(adj[base + lane] != 0);
      if (lane == 0) adjb64[base >> 6] = m;
    }
    return;
  }
  const int gb = blockIdx.x - 1024;
  const int xcd = gb & 7, fq = xcd & 3, b1 = xcd >> 2;
  const int slot = gb >> 3, ntl = slot & 63, b2 = slot >> 6;
  const int b = b2 * 2 + b1, nn = ntl * 16, n0g = b * 1024 + nn;

  const int wv = t >> 6, lane = t & 63;
  const int li = lane & 15, kg = lane >> 4;
  const int head = fq * 2 + (wv >> 1);
  const int hb = b * NH + head;
  const int fi0 = (wv & 1) * 16;

  {
    const int hr = t >> 4, hk = (t & 15) * 8;
    const float4 v0 = *(const float4*)&h[(size_t)(n0g + hr) * FIN + hk];
    const float4 v1 = *(const float4*)&h[(size_t)(n0g + hr) * FIN + hk + 4];
    half8 o;
    o[0]=(_Float16)v0.x; o[1]=(_Float16)v0.y; o[2]=(_Float16)v0.z; o[3]=(_Float16)v0.w;
    o[4]=(_Float16)v1.x; o[5]=(_Float16)v1.y; o[6]=(_Float16)v1.z; o[7]=(_Float16)v1.w;
    *(half8*)&h16s[hr][hk] = o;
  }
  {
    const int fl = t & 63;
#pragma unroll 8
    for (int kk = t >> 6; kk < FIN; kk += 4)
      wt16s[fl][kk] = (_Float16)W[(size_t)kk * FOUT + fq * 64 + fl];
  }
  __syncthreads();

  const _Float16* arow = &wt16s[wv * 16 + li][kg * 8];
  f32x4 acc = {0.f, 0.f, 0.f, 0.f};
#pragma unroll
  for (int ks = 0; ks < 4; ++ks) {
    const half8 Af = *(const half8*)(arow + ks * 32);
    const half8 Bf = *(const half8*)&h16s[li][ks * 32 + kg * 8];
    acc = __builtin_amdgcn_mfma_f32_16x16x32_f16(Af, Bf, acc, 0, 0, 0);
  }
  float pl = 0.f, pr = 0.f;
#pragma unroll
  for (int r = 0; r < 4; ++r) {
    const int fi = fi0 + kg * 4 + r;
    g16[((size_t)hb * ND + fi) * N_ + nn + li] = (_Float16)acc[r];
    pl += a_vec[fi] * acc[r];
    pr += a_vec[ND + fi] * acc[r];
  }
  pl *= LOG2E; pr *= LOG2E;
  pl += __shfl_xor(pl, 16); pl += __shfl_xor(pl, 32);
  pr += __shfl_xor(pr, 16); pr += __shfl_xor(pr, 32);
  if (lane < 16) { elp[wv][li] = pl; erp[wv][li] = pr; }
  __syncthreads();
  if (t < 32) {
    const int hh = t >> 4, ll = t & 15;
    const int hbw = b * NH + fq * 2 + hh;
    elt[(size_t)hbw * N_ + nn + ll] = elp[2*hh][ll] + elp[2*hh+1][ll];
    ert[(size_t)hbw * N_ + nn + ll] = erp[2*hh][ll] + erp[2*hh+1][ll];
  }
}

__global__ __launch_bounds__(1024) void gat_kC(
    const unsigned* __restrict__ adjb, const _Float16* __restrict__ g16,
    const float* __restrict__ elt, const float* __restrict__ ert,
    float* __restrict__ out)
{
  __shared__ P2Smem s2;
  const int t = threadIdx.x;
  const int u0 = blockIdx.x;
  const int xcd = u0 & 7, fq = xcd & 3, b1 = xcd >> 2;
  const int slot = u0 >> 3;
  const int it = slot & 15, hp = (slot >> 4) & 1, b2 = slot >> 5;
  const int head = fq * 2 + hp, b = b2 * 2 + b1, i0 = it * 64;
  const int w16 = t >> 6, lane = t & 63;
  const int li = lane & 15, kg = lane >> 4, kg8 = kg * 8;
  kc_body(&s2, adjb, g16, elt, ert, out, b, head, i0, t, w16, lane, li, kg, kg8);
}

extern "C" void kernel_launch(void* const* d_in, const int* in_sizes, int n_in,
                              void* d_out, int out_size, void* d_ws, size_t ws_size,
                              hipStream_t stream) {
  const float* h     = (const float*)d_in[0];
  const int*   adj   = (const int*)d_in[1];
  const float* W     = (const float*)d_in[2];
  const float* a_vec = (const float*)d_in[3];
  float* out = (float*)d_out;

  char* ws = (char*)d_ws;
  _Float16* g16  = (_Float16*)(ws);
  float*    elt  = (float*)(ws + (2u << 20));
  float*    ert  = (float*)(ws + (2u << 20) + (128u << 10));
  unsigned long long* adjb64 = (unsigned long long*)(ws + (2560u << 10));

  void* args[] = {(void*)&adj, (void*)&adjb64, (void*)&W, (void*)&h,
                  (void*)&a_vec, (void*)&g16, (void*)&elt, (void*)&ert, (void*)&out};
  hipError_t e = hipLaunchCooperativeKernel((const void*)gat_fused, dim3(256),
                                            dim3(1024), args, 0, stream);
  if (e != hipSuccess) {
    (void)hipGetLastError();   // clear sticky error; use proven 2-kernel path
    gat_kAB<<<2048, 256, 0, stream>>>(adj, adjb64, W, h, a_vec, g16, elt, ert);
    gat_kC<<<512, 1024, 0, stream>>>((const unsigned*)adjb64, g16, elt, ert, out);
  }
}

// Round 20
// 29.164 us; speedup vs baseline: 2.3938x; 2.3938x over previous
//
#include <hip/hip_runtime.h>

#define B_    4
#define N_    1024
#define FIN   128
#define FOUT  256
#define NH    8
#define ND    32
#define NSL   0.2f
#define LOG2E 1.44269504088896340736f

typedef _Float16 half8 __attribute__((ext_vector_type(8)));
typedef _Float16 h2 __attribute__((ext_vector_type(2)));
typedef __fp16 fp16x2 __attribute__((ext_vector_type(2)));
typedef float f32x4 __attribute__((ext_vector_type(4)));

static __device__ __forceinline__ unsigned bc_u(h2 v) {
  union { h2 h; unsigned u; } c; c.h = v; return c.u;
}
static __device__ __forceinline__ h2 bc_h(unsigned v) {
  union { h2 h; unsigned u; } c; c.u = v; return c.h;
}

// ---- kAB: blocks [0,1024): bit-pack adj via ballot (512KB total);
//      blocks [1024,2048): g = h@W MFMA, W f16-staged in LDS; el/er LDS combine.
__global__ __launch_bounds__(256) void gat_kAB(
    const int* __restrict__ adj, unsigned long long* __restrict__ adjb64,
    const float* __restrict__ W, const float* __restrict__ h,
    const float* __restrict__ a_vec, _Float16* __restrict__ g16,
    float* __restrict__ elt, float* __restrict__ ert)
{
  __shared__ _Float16 h16s[16][136];
  __shared__ _Float16 wt16s[64][136];
  __shared__ float elp[4][16], erp[4][16];

  const int t = threadIdx.x;

  if (blockIdx.x < 1024) {          // ---- bitmask branch (HBM-bound) ----
    const int gw = (blockIdx.x * 256 + t) >> 6;
    const int lane = t & 63;
    const size_t base0 = (size_t)gw * 1024;
#pragma unroll
    for (int it = 0; it < 16; ++it) {
      const size_t base = base0 + it * 64;
      const unsigned long long m = __ballot(adj[base + lane] != 0);
      if (lane == 0) adjb64[base >> 6] = m;
    }
    return;
  }

  // ---- gemm branch ----
  const int gb = blockIdx.x - 1024;
  const int fq = gb & 3;
  const int nt = gb >> 2;
  const int n0 = nt * 16;
  const int b = n0 >> 10, nn = n0 & 1023;
  const int fbase = fq * 64;

  const int wv = t >> 6, lane = t & 63;
  const int li = lane & 15, kg = lane >> 4;
  const int head = fq * 2 + (wv >> 1);
  const int hb   = b * NH + head;
  const int fi0  = (wv & 1) * 16;

  {   // stage h rows n0..n0+15 (f32 -> f16)
    const int hr = t >> 4, hk = (t & 15) * 8;
    const float4 v0 = *(const float4*)&h[(size_t)(n0 + hr) * FIN + hk];
    const float4 v1 = *(const float4*)&h[(size_t)(n0 + hr) * FIN + hk + 4];
    half8 o;
    o[0]=(_Float16)v0.x; o[1]=(_Float16)v0.y; o[2]=(_Float16)v0.z; o[3]=(_Float16)v0.w;
    o[4]=(_Float16)v1.x; o[5]=(_Float16)v1.y; o[6]=(_Float16)v1.z; o[7]=(_Float16)v1.w;
    *(half8*)&h16s[hr][hk] = o;
  }
  {   // stage W^T slice (f32 -> f16), L2-hot
    const int fl = t & 63;
#pragma unroll 8
    for (int kk = t >> 6; kk < FIN; kk += 4)
      wt16s[fl][kk] = (_Float16)W[(size_t)kk * FOUT + fbase + fl];
  }
  __syncthreads();

  const _Float16* __restrict__ arow = &wt16s[wv * 16 + li][kg * 8];

  f32x4 acc = {0.f, 0.f, 0.f, 0.f};
#pragma unroll
  for (int ks = 0; ks < 4; ++ks) {
    const half8 Af = *(const half8*)(arow + ks * 32);
    const half8 Bf = *(const half8*)&h16s[li][ks * 32 + kg * 8];
    acc = __builtin_amdgcn_mfma_f32_16x16x32_f16(Af, Bf, acc, 0, 0, 0);
  }

  float pl = 0.f, pr = 0.f;
#pragma unroll
  for (int r = 0; r < 4; ++r) {
    const int fi = fi0 + kg * 4 + r;
    g16[((size_t)hb * ND + fi) * N_ + nn + li] = (_Float16)acc[r];
    pl += a_vec[fi] * acc[r];
    pr += a_vec[ND + fi] * acc[r];
  }
  pl *= LOG2E; pr *= LOG2E;
  pl += __shfl_xor(pl, 16); pl += __shfl_xor(pl, 32);
  pr += __shfl_xor(pr, 16); pr += __shfl_xor(pr, 32);
  if (lane < 16) { elp[wv][li] = pl; erp[wv][li] = pr; }
  __syncthreads();

  if (t < 32) {
    const int hh = t >> 4, ll = t & 15;
    const int hbw = b * NH + fq * 2 + hh;
    elt[(size_t)hbw * N_ + nn + ll] = elp[2 * hh][ll] + elp[2 * hh + 1][ll];
    ert[(size_t)hbw * N_ + nn + ll] = erp[2 * hh][ll] + erp[2 * hh + 1][ll];
  }
}

// AND-word from 2 adj bits (pure VALU): sbfe sign-extend + perm pack
#define MASKW(SH, Q)                                                            \
  __builtin_amdgcn_perm(                                                        \
      (unsigned)__builtin_amdgcn_sbfe((int)(SH), 2*(Q)+1, 1),                   \
      (unsigned)__builtin_amdgcn_sbfe((int)(SH), 2*(Q), 1), 0x07060100u)

// packed pair: x = el2+er2 (pk), lrelu (pk), exp f16 lo+hi, repack, AND-mask
#define PGEN_PAIR(EL2, ERW, MAW, OUTW)                                          \
  {                                                                             \
    h2 x = (EL2) + bc_h(ERW);                                                   \
    h2 y = x * nsl2;                                                            \
    x = __builtin_elementwise_max(x, y);                                        \
    const unsigned xu = bc_u(x);                                                \
    const unsigned xh = xu >> 16;                                               \
    unsigned plo, phi;                                                          \
    asm("v_exp_f16 %0, %1" : "=v"(plo) : "v"(xu));                              \
    asm("v_exp_f16 %0, %1" : "=v"(phi) : "v"(xh));                              \
    (OUTW) = __builtin_amdgcn_perm(phi, plo, 0x05040100u) & (MAW);              \
  }

// ---- kC: block=(b,head,64-i tile), 1024 thr / 16 waves (8 j-splits x 2 i-halves).
// Per wave: 32 i x 32 f x 128 j. Packed-f16 P-gen, pure-VALU masking.
__global__ __launch_bounds__(1024) void gat_kC(
    const unsigned* __restrict__ adjb, const _Float16* __restrict__ g16,
    const float* __restrict__ elt, const float* __restrict__ ert,
    float* __restrict__ out)
{
  __shared__ _Float16 er_h[N_];          // 2 KB
  __shared__ float dpart[8][32][68];     // 69.6 KB
  __shared__ float denp[8][64];          // 2 KB

  const int t = threadIdx.x;
  const int u0 = blockIdx.x;
  const int v  = ((u0 & 7) << 6) | (u0 >> 3);   // XCD swizzle (512 = 8*64)
  const int it   = v & 15;
  const int head = (v >> 4) & 7;
  const int b    = v >> 7;
  const int i0   = it * 64;
  const int hb   = b * NH + head;

  const int w16 = t >> 6;                // wave 0..15
  const int wv  = w16 >> 1;              // j-split 0..7
  const int ih  = w16 & 1;               // i-half
  const int lane = t & 63;
  const int li = lane & 15, kg = lane >> 4, kg8 = kg * 8;
  const h2 nsl2 = {(_Float16)NSL, (_Float16)NSL};

  // stage er as f16: all 1024 threads, one element each
  er_h[t] = (_Float16)ert[(size_t)hb * N_ + t];
  __syncthreads();

  const int rowA = i0 + ih * 32 + li;
  const int rowB = rowA + 16;
  const float el_a = elt[(size_t)hb * N_ + rowA];
  const float el_b = elt[(size_t)hb * N_ + rowB];
  union { fp16x2 hh; unsigned u; h2 h; } ca, cb;
  ca.hh = __builtin_amdgcn_cvt_pkrtz(el_a, el_a);
  cb.hh = __builtin_amdgcn_cvt_pkrtz(el_b, el_b);
  const h2 el2a = ca.h, el2b = cb.h;

  const int4 A  = ((const int4*)(adjb + (size_t)(b * N_ + rowA) * 32))[wv];
  const int4 Bm = ((const int4*)(adjb + (size_t)(b * N_ + rowB) * 32))[wv];
  const unsigned wA[4] = {(unsigned)A.x, (unsigned)A.y, (unsigned)A.z, (unsigned)A.w};
  const unsigned wB[4] = {(unsigned)Bm.x, (unsigned)Bm.y, (unsigned)Bm.z, (unsigned)Bm.w};

  const _Float16* __restrict__ arow0 =
      g16 + ((size_t)hb * ND + li) * N_ + wv * 128 + kg8;
  const _Float16* __restrict__ arow1 = arow0 + (size_t)16 * N_;

  f32x4 acc0 = {0,0,0,0}, acc1 = {0,0,0,0}, accd = {0,0,0,0};
  f32x4 acc0b = {0,0,0,0}, acc1b = {0,0,0,0}, accdb = {0,0,0,0};
  const half8 ones = {(_Float16)1.f, (_Float16)1.f, (_Float16)1.f, (_Float16)1.f,
                      (_Float16)1.f, (_Float16)1.f, (_Float16)1.f, (_Float16)1.f};

#pragma unroll
  for (int u = 0; u < 4; ++u) {
    const half8 Ag0 = *(const half8*)(arow0 + u * 32);
    const half8 Ag1 = *(const half8*)(arow1 + u * 32);
    const uint4 erv = *(const uint4*)&er_h[wv * 128 + u * 32 + kg8];
    const unsigned erw[4] = {erv.x, erv.y, erv.z, erv.w};

    const unsigned shA = wA[u] >> kg8;
    const unsigned shB = wB[u] >> kg8;

    union { half8 h8; unsigned uu[4]; } PA, PB;
#pragma unroll
    for (int q = 0; q < 4; ++q) {
      const unsigned maA = MASKW(shA, q);
      const unsigned maB = MASKW(shB, q);
      PGEN_PAIR(el2a, erw[q], maA, PA.uu[q])
      PGEN_PAIR(el2b, erw[q], maB, PB.uu[q])
    }

    acc0  = __builtin_amdgcn_mfma_f32_16x16x32_f16(Ag0, PA.h8, acc0, 0, 0, 0);
    acc1  = __builtin_amdgcn_mfma_f32_16x16x32_f16(Ag1, PA.h8, acc1, 0, 0, 0);
    accd  = __builtin_amdgcn_mfma_f32_16x16x32_f16(ones, PA.h8, accd, 0, 0, 0);
    acc0b = __builtin_amdgcn_mfma_f32_16x16x32_f16(Ag0, PB.h8, acc0b, 0, 0, 0);
    acc1b = __builtin_amdgcn_mfma_f32_16x16x32_f16(Ag1, PB.h8, acc1b, 0, 0, 0);
    accdb = __builtin_amdgcn_mfma_f32_16x16x32_f16(ones, PB.h8, accdb, 0, 0, 0);
  }

  const int ci = ih * 32 + li;
#pragma unroll
  for (int r = 0; r < 4; ++r) {
    dpart[wv][4*kg + r][ci]           = acc0[r];
    dpart[wv][16 + 4*kg + r][ci]      = acc1[r];
    dpart[wv][4*kg + r][16 + ci]      = acc0b[r];
    dpart[wv][16 + 4*kg + r][16 + ci] = acc1b[r];
  }
  if (lane < 16) { denp[wv][ci] = accd[0]; denp[wv][16 + ci] = accdb[0]; }
  __syncthreads();

  for (int o = t; o < 2048; o += 1024) {
    const int f = o & 31, ii = o >> 5;     // ii 0..63
    float s = 0.f, dn = 0.f;
#pragma unroll
    for (int p = 0; p < 8; ++p) { s += dpart[p][f][ii]; dn += denp[p][ii]; }
    float w = s / dn;
    w = fmaxf(w, NSL * w);
    out[((size_t)(b * N_ + i0 + ii)) * FOUT + head * ND + f] = w;
  }
}

extern "C" void kernel_launch(void* const* d_in, const int* in_sizes, int n_in,
                              void* d_out, int out_size, void* d_ws, size_t ws_size,
                              hipStream_t stream) {
  const float* h     = (const float*)d_in[0];
  const int*   adj   = (const int*)d_in[1];
  const float* W     = (const float*)d_in[2];
  const float* a_vec = (const float*)d_in[3];
  float* out = (float*)d_out;

  char* ws = (char*)d_ws;
  _Float16* g16  = (_Float16*)(ws);                         // 2 MB
  float*    elt  = (float*)(ws + (2u << 20));               // 128 KB
  float*    ert  = (float*)(ws + (2u << 20) + (128u << 10));
  unsigned long long* adjb64 = (unsigned long long*)(ws + (2560u << 10)); // 512 KB

  gat_kAB<<<2048, 256, 0, stream>>>(adj, adjb64, W, h, a_vec, g16, elt, ert);
  gat_kC<<<512, 1024, 0, stream>>>((const unsigned*)adjb64, g16, elt, ert, out);
}